// Round 7
// baseline (1784.403 us; speedup 1.0000x reference)
//
#include <hip/hip_runtime.h>
#include <hip/hip_fp16.h>

#define T_SZ 365
#define IN_SZ 32
#define H_SZ 256
#define G4 1024
#define K_SZ 288
#define M_BLK 32          // batch rows per group (pair of blocks)
#define M_SLAB 16         // rows per slab; 2 independent slabs pipeline the sync
#define NGRP 128          // groups: 128 * 32 = 4096 rows
#define NTHR 512          // 8 waves, each owns a distinct 16-col W slice
#define NBLK 256          // 1 block per CU
#define XPB 80            // x_s row stride bytes (40 halfs, padded)
#define HROWB 512         // bytes per hs row (256 halfs, dense + XOR swizzle)
#define HSLAB (M_SLAB * HROWB)   // 8 KB per slab h-image
#define HXG 1024          // u64 per (buf,slab,group) hx image: 2 members x 4 KB

// workspace offsets (bytes)
#define ARR_OFF (640*1024)
#define HX_OFF  (1024*1024)

typedef _Float16 f16x8 __attribute__((ext_vector_type(8)));
typedef _Float16 f16x2 __attribute__((ext_vector_type(2)));
typedef float f32x4 __attribute__((ext_vector_type(4)));
typedef unsigned long long u64;

__device__ __forceinline__ float fast_sigmoid(float x) {
    float e = __builtin_amdgcn_exp2f(-1.4426950408889634f * x);
    return __builtin_amdgcn_rcpf(1.0f + e);
}
__device__ __forceinline__ float fast_tanh(float x) {
    float e = __builtin_amdgcn_exp2f(2.8853900817779268f * x);
    return 1.0f - 2.0f * __builtin_amdgcn_rcpf(1.0f + e);
}

// Pack W = [w_hh | w_ih] as fp16, layout [gate-row][k] (k contiguous) = B^T.
__global__ void pack_w_kernel(const float* __restrict__ w_ih,
                              const float* __restrict__ w_hh,
                              _Float16* __restrict__ wp) {
    int idx = blockIdx.x * 256 + threadIdx.x;
    if (idx >= G4 * K_SZ) return;
    int g = idx / K_SZ, k = idx - g * K_SZ;
    float v = (k < H_SZ) ? w_hh[g * H_SZ + k] : w_ih[g * IN_SZ + (k - H_SZ)];
    wp[idx] = (_Float16)v;
}

__global__ void init_sync_kernel(unsigned int* arrive) {
    for (int i = threadIdx.x; i < NGRP * 4 * 16; i += 256) arrive[i] = 0u;
}

// One slab GEMM: 16 rows x 288 @ Wslice^T -> acc[4] (one f32x4 per gate).
#define GEMM_SLAB(acc, hbase, xoff) do {                                                    \
    _Pragma("unroll")                                                                       \
    for (int kt_ = 0; kt_ < 8; ++kt_) {                                                     \
        f16x8 a_ = *(const f16x8*)((const char*)(hbase) + a_off[kt_]);                      \
        _Pragma("unroll")                                                                   \
        for (int G_ = 0; G_ < 4; ++G_)                                                      \
            acc[G_] = __builtin_amdgcn_mfma_f32_16x16x32_f16(a_, wfr[G_][kt_], acc[G_],0,0,0);\
    }                                                                                       \
    {                                                                                       \
        f16x8 a_ = *(const f16x8*)(x_s + (xoff));                                           \
        _Pragma("unroll")                                                                   \
        for (int G_ = 0; G_ < 4; ++G_)                                                      \
            acc[G_] = __builtin_amdgcn_mfma_f32_16x16x32_f16(a_, wfr[G_][8], acc[G_],0,0,0);\
    }                                                                                       \
} while (0)

// Activations + state update for one slab; own 16 cols -> hdst (swizzled).
#define ACT_STORE(acc, creg, hdst) do {                                                     \
    _Pragma("unroll")                                                                       \
    for (int r_ = 0; r_ < 4; ++r_) {                                                        \
        float iv = fast_sigmoid(acc[0][r_] + bias[0]);                                      \
        float fv = fast_sigmoid(acc[1][r_] + bias[1]);                                      \
        float gv = fast_tanh  (acc[2][r_] + bias[2]);                                       \
        float ov = fast_sigmoid(acc[3][r_] + bias[3]);                                      \
        float cv = fv * creg[r_] + iv * gv;                                                 \
        creg[r_] = cv;                                                                      \
        float hv = ov * fast_tanh(cv);                                                      \
        int m_ = quad * 4 + r_;                                                             \
        *(_Float16*)((hdst) + m_ * HROWB + ((jcol * 2) ^ ((m_ & 7) << 4))) = (_Float16)hv;  \
    }                                                                                       \
} while (0)

__global__ __launch_bounds__(NTHR, 2) void lstm_kernel(
    const float* __restrict__ xd, const float* __restrict__ b,
    const _Float16* __restrict__ wp, const float* __restrict__ w_out,
    const float* __restrict__ b_out, float* __restrict__ out,
    u64* hx, unsigned int* arrive)
{
    // per-slab double-buffered h; dense 512-B rows, XOR-swizzled (byte ^= (row&7)<<4)
    __shared__ __align__(16) char hsA[2][HSLAB];            // 16 KB
    __shared__ __align__(16) char hsB[2][HSLAB];            // 16 KB
    __shared__ __align__(16) char x_s[M_BLK * XPB];         // 2.5 KB

    const int tid  = threadIdx.x;
    const int wq   = tid >> 6;        // wave 0..7
    const int lane = tid & 63;
    const int quad = lane >> 4;
    const int l16  = lane & 15;
    const int blk  = blockIdx.x;
    const int g    = blk & (NGRP - 1);
    const int q    = blk >> 7;           // pair member 0/1 (blk, blk+128: same XCD)

    const int jcol = q * 128 + wq * 16 + l16;   // this lane's global h column

    // ---- W slice (4 gates x 16 j-cols x K=288), plain loads (round-3 codegen) ----
    f16x8 wfr[4][9];
#pragma unroll
    for (int G = 0; G < 4; ++G) {
        const _Float16* wr = wp + (size_t)(G * 256 + jcol) * K_SZ + quad * 8;
#pragma unroll
        for (int kt = 0; kt < 9; ++kt)
            wfr[G][kt] = *(const f16x8*)(wr + kt * 32);
    }
    float bias[4];
#pragma unroll
    for (int G = 0; G < 4; ++G) bias[G] = b[G * 256 + jcol];

    // ---- loop-invariant swizzled A-read offsets (rows 0..15 of a slab) ----
    const int swz_l = (l16 & 7) << 4;
    int a_off[8];
#pragma unroll
    for (int kt = 0; kt < 8; ++kt)
        a_off[kt] = l16 * HROWB + ((kt * 64 + quad * 16) ^ swz_l);
    const int x_offA = l16 * XPB + quad * 16;
    const int x_offB = x_offA + M_SLAB * XPB;

    // x loader: 32 rows, 16 threads/row, 2 floats each
    const int xr = tid >> 4;
    const int xe = tid & 15;
    const int xs_byte = xr * XPB + xe * 4;
    const float* xrow = xd + (size_t)(g * M_BLK + xr) * (T_SZ * IN_SZ) + xe * 2;

    // ---- per-wave push: wave pushes its own 16 cols x 16 rows (512 B, full lines) ----
    const int prow = lane >> 2;          // 0..15
    const int pch  = lane & 3;           // 8-B chunk within wave's 32-B row slice
    const int push_lb = prow * HROWB + ((q * 256 + wq * 32 + pch * 8) ^ ((prow & 7) << 4));
    const int push_u  = q * 512 + wq * 64 + lane;     // hx u64 idx, wave-major
    // pull: partner 4-KB region, 8 B per thread; decode [wave'][row][chunk]
    const int pwv = tid >> 6, prw = (tid & 63) >> 2, pcc = tid & 3;
    const int pull_u  = (1 - q) * 512 + tid;
    const int pull_lb = prw * HROWB + (((1 - q) * 256 + pwv * 32 + pcc * 8) ^ ((prw & 7) << 4));

    // zero h_0 (both slabs, buffer 0)
    {
        u64* zA = (u64*)&hsA[0][0];
        u64* zB = (u64*)&hsB[0][0];
        zA[tid] = 0ull; zA[tid + 512] = 0ull;
        zB[tid] = 0ull; zB[tid + 512] = 0ull;
    }
    // stage x_0
    {
        float2 x0 = *(const float2*)xrow;
        *(f16x2*)(x_s + xs_byte) = (f16x2){(_Float16)x0.x, (_Float16)x0.y};
    }

    f32x4 cregA = (f32x4){0.f, 0.f, 0.f, 0.f};
    f32x4 cregB = (f32x4){0.f, 0.f, 0.f, 0.f};
    const f32x4 vzero = {0.f, 0.f, 0.f, 0.f};

    __syncthreads();   // prologue drain: nothing in flight entering the loop

    unsigned int* myfA = &arrive[(g * 4 + q * 2 + 0) * 16];
    unsigned int* prfA = &arrive[(g * 4 + (1 - q) * 2 + 0) * 16];
    unsigned int* myfB = myfA + 16;
    unsigned int* prfB = prfA + 16;

    float2 xa = {0.f, 0.f};
    u64 pvb = 0;   // pulled slab-B partner data from previous iteration
    int pb = 0;    // pb == t&1; h_t lives in buffer pb

    for (int t = 0; t < T_SZ; ++t) {
        char* hsA_R = hsA[pb];     char* hsA_W = hsA[pb ^ 1];
        char* hsB_R = hsB[pb];     char* hsB_W = hsB[pb ^ 1];
        u64* hxA = hx + ((size_t)(((pb ^ 1) << 1) + 0) * NGRP + g) * HXG;
        u64* hxB = hx + ((size_t)(((pb ^ 1) << 1) + 1) * NGRP + g) * HXG;

        // ================= P1: slab A compute + push =================
        f32x4 accA[4];
#pragma unroll
        for (int G = 0; G < 4; ++G) accA[G] = vzero;
        GEMM_SLAB(accA, hsA_R, x_offA);
        ACT_STORE(accA, cregA, hsA_W);
        asm volatile("s_waitcnt lgkmcnt(0)" ::: "memory");   // own-wave h writes done
        {
            u64 pa = *(const u64*)(hsA_W + push_lb);         // own wave's data only
            __hip_atomic_store(&hxA[push_u], pa, __ATOMIC_RELAXED, __HIP_MEMORY_SCOPE_AGENT);
        }
        {   // prefetch x_{t+1} (stays in flight until P4)
            int tn = (t + 1 < T_SZ) ? t + 1 : T_SZ - 1;
            xa = *(const float2*)(xrow + (size_t)tn * IN_SZ);
        }
        // drain pvb(t-1) + push_A; keep x load in flight
        asm volatile("s_waitcnt vmcnt(1)" ::: "memory");
        if (t > 0)
            *(u64*)(hsB_R + pull_lb) = pvb;                  // complete h_t slab B
        asm volatile("s_waitcnt lgkmcnt(0)" ::: "memory");
        __builtin_amdgcn_s_barrier();                        // A pushed; h_t(B) complete
        if (tid == 0) {
            __hip_atomic_store(myfA, (unsigned int)(t + 1), __ATOMIC_RELAXED, __HIP_MEMORY_SCOPE_AGENT);
            while (__hip_atomic_load(prfA, __ATOMIC_RELAXED, __HIP_MEMORY_SCOPE_AGENT) < (unsigned int)(t + 1))
                __builtin_amdgcn_s_sleep(1);
        }
        __builtin_amdgcn_s_barrier();
        // issue pull of partner slab-A half (flight covered by slab B compute)
        u64 pva = __hip_atomic_load(&hxA[pull_u], __ATOMIC_RELAXED, __HIP_MEMORY_SCOPE_AGENT);

        // ================= P3: slab B compute + push =================
        f32x4 accB[4];
#pragma unroll
        for (int G = 0; G < 4; ++G) accB[G] = vzero;
        GEMM_SLAB(accB, hsB_R, x_offB);
        ACT_STORE(accB, cregB, hsB_W);
        asm volatile("s_waitcnt lgkmcnt(0)" ::: "memory");
        {
            u64 pbv = *(const u64*)(hsB_W + push_lb);
            __hip_atomic_store(&hxB[push_u], pbv, __ATOMIC_RELAXED, __HIP_MEMORY_SCOPE_AGENT);
        }

        // ================= P4: finish A-pull, exchange B =================
        asm volatile("s_waitcnt vmcnt(0)" ::: "memory");     // pva arrived; B pushed; x arrived
        *(u64*)(hsA_W + pull_lb) = pva;                      // complete h_{t+1} slab A
        asm volatile("s_waitcnt lgkmcnt(0)" ::: "memory");
        __builtin_amdgcn_s_barrier();                        // all waves past P3 x-reads
        if (t + 1 < T_SZ)
            *(f16x2*)(x_s + xs_byte) = (f16x2){(_Float16)xa.x, (_Float16)xa.y};
        if (tid == 0) {
            __hip_atomic_store(myfB, (unsigned int)(t + 1), __ATOMIC_RELAXED, __HIP_MEMORY_SCOPE_AGENT);
            while (__hip_atomic_load(prfB, __ATOMIC_RELAXED, __HIP_MEMORY_SCOPE_AGENT) < (unsigned int)(t + 1))
                __builtin_amdgcn_s_sleep(1);
        }
        asm volatile("s_waitcnt lgkmcnt(0)" ::: "memory");
        __builtin_amdgcn_s_barrier();                        // x_{t+1} staged; B flags done
        // issue pull of partner slab-B half (flight covered by next P1)
        pvb = __hip_atomic_load(&hxB[pull_u], __ATOMIC_RELAXED, __HIP_MEMORY_SCOPE_AGENT);
        pb ^= 1;
    }

    // ---- epilogue: complete h_T slab B with final pulled half ----
    asm volatile("s_waitcnt vmcnt(0)" ::: "memory");
    *(u64*)(hsB[pb] + pull_lb) = pvb;
    asm volatile("s_waitcnt lgkmcnt(0)" ::: "memory");
    __builtin_amdgcn_s_barrier();

    // out[m] = relu(h_T . w_out + b_out); member q==0 writes
    if (q == 0) {
        const int m = tid >> 4, p = tid & 15;
        const char* hsF = (m < M_SLAB ? hsA[pb] : hsB[pb]) + (m & 15) * HROWB;
        const int swzm = (m & 7) << 4;
        float sum = 0.f;
#pragma unroll
        for (int jj = 0; jj < 16; ++jj) {
            int j = p * 16 + jj;
            sum += (float)*(const _Float16*)(hsF + ((j * 2) ^ swzm)) * w_out[j];
        }
        sum += __shfl_xor(sum, 1);
        sum += __shfl_xor(sum, 2);
        sum += __shfl_xor(sum, 4);
        sum += __shfl_xor(sum, 8);
        if (p == 0) out[(size_t)g * M_BLK + m] = fmaxf(sum + b_out[0], 0.f);
    }
}

extern "C" void kernel_launch(void* const* d_in, const int* in_sizes, int n_in,
                              void* d_out, int out_size, void* d_ws, size_t ws_size,
                              hipStream_t stream) {
    const float* xd    = (const float*)d_in[0];
    const float* w_ih  = (const float*)d_in[1];
    const float* w_hh  = (const float*)d_in[2];
    const float* b     = (const float*)d_in[3];
    const float* w_out = (const float*)d_in[4];
    const float* b_out = (const float*)d_in[5];
    float* out = (float*)d_out;

    _Float16* wp = (_Float16*)d_ws;                                 // 576 KB @ 0
    unsigned int* arrive = (unsigned int*)((char*)d_ws + ARR_OFF);  // 32 KB
    u64* hx = (u64*)((char*)d_ws + HX_OFF);                         // 4 MB

    pack_w_kernel<<<(G4 * K_SZ + 255) / 256, 256, 0, stream>>>(w_ih, w_hh, wp);
    init_sync_kernel<<<1, 256, 0, stream>>>(arrive);
    lstm_kernel<<<NBLK, NTHR, 0, stream>>>(xd, b, wp, w_out, b_out, out, hx, arrive);
}